// Round 12
// baseline (346.632 us; speedup 1.0000x reference)
//
#include <hip/hip_runtime.h>
#include <hip/hip_bf16.h>

// GAT: 2-layer, N=50000, F=64, H=4, C=64, D=256, E=800000 (+N self loops)
// out = softmax(mean_pool(layer2) @ cls_W + cls_b) -> [1,16] f32
// Datapath: bf16 MFMA GEMMs (f32 accum, fused attention dots); layer-0 GEMM reads
// f32 x directly (in-register v_cvt_pk_bf16_f32). fp8(e4m3) message gathers
// (16 lanes/row, dwordx4, exact-4 software-pipelined, pk-dequant, v_pk_fma_f32).
// Softmax: no-max-subtraction (logits bounded ~|2|), rcp normalization.
// Graph: XCD-grouped direct scatter into fixed-stride (64) adjacency;
// self-loops virtual in k_agg.  [fp4 messages tried R11: FAILED accuracy; fp8 is the floor]

#define NEG_SLOPE 0.2f
#define MAXDEG 64             // adjacency stride; true max degree ~45 (Poisson 16)
#define NGROUP 8              // == #XCDs; blockIdx&7 -> XCD (perf heuristic only)

__device__ __forceinline__ float leaky(float e) { return fmaxf(e, NEG_SLOPE * e); }

typedef __bf16 bf16x8 __attribute__((ext_vector_type(8)));
typedef float  f32x4  __attribute__((ext_vector_type(4)));
typedef float  f32x2  __attribute__((ext_vector_type(2)));

#if __has_builtin(__builtin_amdgcn_cvt_pk_f32_fp8) && __has_builtin(__builtin_amdgcn_cvt_pk_fp8_f32)
#define USE_FP8 1
#else
#define USE_FP8 0
#endif

__device__ __forceinline__ float bfbits2f(unsigned int hi_bits) {
    union { unsigned int i; float f; } c; c.i = hi_bits; return c.f;
}
__device__ __forceinline__ unsigned short f2bf(float f) {
    union { float f; unsigned int i; } c; c.f = f;
    unsigned int x = c.i;
    x += 0x7fffu + ((x >> 16) & 1u);   // RNE
    return (unsigned short)(x >> 16);
}
__device__ __forceinline__ f32x2 pkfma(f32x2 a, f32x2 b, f32x2 c) {
    f32x2 d;
    asm("v_pk_fma_f32 %0, %1, %2, %3" : "=v"(d) : "v"(a), "v"(b), "v"(c));
    return d;
}
__device__ __forceinline__ unsigned int cvt_pk_bf16(float a, float b) {
    unsigned int r;
    asm("v_cvt_pk_bf16_f32 %0, %1, %2" : "=v"(r) : "v"(a), "v"(b));
    return r;
}

// ---------------- prep: zero cursor/pooled + weight transposes (1 small kernel) ----------------
// sections by blockIdx: [0,64) W0T ; [64,320) W1T ; [320,..) zero cursor/pooled

__global__ void k_prep(const float* __restrict__ W0, unsigned short* __restrict__ W0T,
                       const float* __restrict__ W1, unsigned short* __restrict__ W1T,
                       int* __restrict__ cursor, float* __restrict__ pooled, int N) {
    const int b = blockIdx.x, t = threadIdx.x;
    if (b < 64) {
        int i = b * 256 + t;                // i < 16384
        int k = i & 63, c = i >> 6;
        W0T[(size_t)c * 64 + k] = f2bf(W0[(size_t)k * 256 + c]);
    } else if (b < 320) {
        int i = (b - 64) * 256 + t;         // i < 65536
        int k = i & 255, c = i >> 8;
        W1T[(size_t)c * 256 + k] = f2bf(W1[(size_t)k * 256 + c]);
    } else {
        int i = (b - 320) * 256 + t;
        if (i < N) cursor[i] = 0;
        if (b == 320) pooled[t] = 0.f;
    }
}

// ---------------- graph build: XCD-grouped direct scatter ----------------

__global__ __launch_bounds__(256) void k_fill_xcd(const int* __restrict__ ei,
                                                  int* __restrict__ cursor,
                                                  int* __restrict__ adj, int N, int E) {
    const int g = blockIdx.x & (NGROUP - 1);
    const int bg = blockIdx.x >> 3;
    const int nbg = gridDim.x >> 3;
    const int chunk = (N + NGROUP - 1) / NGROUP;
    const int lo = g * chunk;
    const int hi = min(N, lo + chunk);
    for (int i = bg * 256 + threadIdx.x; i < E; i += nbg * 256) {
        int d = ei[E + i];
        if (d >= lo && d < hi) {
            int s = ei[i];
            int pos = atomicAdd(&cursor[d], 1);
            if (pos < MAXDEG) adj[(size_t)d * MAXDEG + pos] = s;
        }
    }
}

// ---------------- MFMA GEMM + fused attention dots ----------------
// AF32: A operand is f32 in memory, converted in-register to bf16 (layer 0).

template<int K, bool AF32>
__global__ __launch_bounds__(256) void k_gemm_mfma(const void* __restrict__ Xin,
                                                   const unsigned short* __restrict__ WT,
                                                   const float* __restrict__ asrc,
                                                   const float* __restrict__ adst,
                                                   unsigned char* __restrict__ P,
                                                   float* __restrict__ alsrc,
                                                   float* __restrict__ aldst, int N) {
    const int t = threadIdx.x;
    const int w = t >> 6;
    const int l = t & 63;
    const int l16 = l & 15;
    const int lg = l >> 4;
    const int row0 = blockIdx.x * 64;
    const int colbase = w * 64;

    f32x4 acc[4][4];
#pragma unroll
    for (int i = 0; i < 4; ++i)
#pragma unroll
        for (int j = 0; j < 4; ++j) acc[i][j] = (f32x4){0.f, 0.f, 0.f, 0.f};

#pragma unroll
    for (int k0 = 0; k0 < K; k0 += 32) {
        bf16x8 a[4], b[4];
#pragma unroll
        for (int fi = 0; fi < 4; ++fi) {
            int r = row0 + fi * 16 + l16;
            r = (r < N) ? r : (N - 1);
            if constexpr (AF32) {
                const float* Xf = (const float*)Xin;
                float4 lo = *(const float4*)&Xf[(size_t)r * K + k0 + lg * 8];
                float4 hi = *(const float4*)&Xf[(size_t)r * K + k0 + lg * 8 + 4];
                uint4 q;
                q.x = cvt_pk_bf16(lo.x, lo.y);
                q.y = cvt_pk_bf16(lo.z, lo.w);
                q.z = cvt_pk_bf16(hi.x, hi.y);
                q.w = cvt_pk_bf16(hi.z, hi.w);
                union { uint4 u; bf16x8 v; } cv; cv.u = q;
                a[fi] = cv.v;
            } else {
                const unsigned short* Xb = (const unsigned short*)Xin;
                a[fi] = *(const bf16x8*)&Xb[(size_t)r * K + k0 + lg * 8];
            }
        }
#pragma unroll
        for (int fj = 0; fj < 4; ++fj) {
            int c = colbase + fj * 16 + l16;
            b[fj] = *(const bf16x8*)&WT[(size_t)c * K + k0 + lg * 8];
        }
#pragma unroll
        for (int fi = 0; fi < 4; ++fi)
#pragma unroll
            for (int fj = 0; fj < 4; ++fj)
                acc[fi][fj] = __builtin_amdgcn_mfma_f32_16x16x32_bf16(a[fi], b[fj], acc[fi][fj], 0, 0, 0);
    }

    float aSv[4], aDv[4];
#pragma unroll
    for (int fj = 0; fj < 4; ++fj) {
        aSv[fj] = asrc[colbase + fj * 16 + l16];
        aDv[fj] = adst[colbase + fj * 16 + l16];
    }
#pragma unroll
    for (int fi = 0; fi < 4; ++fi) {
#pragma unroll
        for (int r = 0; r < 4; ++r) {
            int row = row0 + fi * 16 + lg * 4 + r;
            bool ok = (row < N);
            float ps = 0.f, pd = 0.f;
#pragma unroll
            for (int fj = 0; fj < 4; ++fj) {
                float v = acc[fi][fj][r];
                if (ok) {
#if USE_FP8
                    unsigned int q = __builtin_amdgcn_cvt_pk_fp8_f32(v, v, 0u, false);
                    P[(size_t)row * 256 + colbase + fj * 16 + l16] = (unsigned char)(q & 0xff);
#else
                    ((unsigned short*)P)[(size_t)row * 256 + colbase + fj * 16 + l16] = f2bf(v);
#endif
                }
                ps = fmaf(v, aSv[fj], ps);
                pd = fmaf(v, aDv[fj], pd);
            }
#pragma unroll
            for (int off = 1; off < 16; off <<= 1) {
                ps += __shfl_xor(ps, off, 64);
                pd += __shfl_xor(pd, off, 64);
            }
            if (ok && l16 == 0) {
                alsrc[(size_t)row * 4 + w] = ps;
                aldst[(size_t)row * 4 + w] = pd;
            }
        }
    }
}

// ---------------- aggregation: one WAVE per dst node ----------------
// softmax: lane owns one edge; NO max subtraction (|logit| <~ 2, f32 exp safe);
// sum via 6-stage shfl; normalize via rcp.
// gather: 16 lanes per source row (dwordx4 = 16 fp8 ch/lane); exact groups of 4
// edges with a 2-deep software pipeline. Padded slots (<=3): weight 0, row d.

__global__ __launch_bounds__(256) void k_agg(const unsigned char* __restrict__ P,
                                             const float* __restrict__ alsrc,
                                             const float* __restrict__ aldst,
                                             const int* __restrict__ degv,
                                             const int* __restrict__ adj,
                                             const float* __restrict__ bias,
                                             unsigned short* __restrict__ out, int N, int do_elu) {
    const int wv = threadIdx.x >> 6;
    const int lane = threadIdx.x & 63;
    const int d = blockIdx.x * 4 + wv;
    __shared__ float s_w[4][256];
    __shared__ int s_off[4][64];
    if (d >= N) return;

    const int deg_e = min(degv[d], MAXDEG - 1);  // <= 63 real edges
    const int deg = deg_e + 1;                   // + virtual self loop
    const int* arow = adj + (size_t)d * MAXDEG;
    const float4 ad = *(const float4*)&aldst[(size_t)d * 4];

    // ---- per-lane edge logits ----
    const bool valid = lane < deg;
    int s = d;                                    // self loop / padding default
    if (lane < deg_e) s = arow[lane];
    float4 as = *(const float4*)&alsrc[(size_t)s * 4];
    float4 e0;
    if (valid) {
        e0.x = leaky(as.x + ad.x); e0.y = leaky(as.y + ad.y);
        e0.z = leaky(as.z + ad.z); e0.w = leaky(as.w + ad.w);
    } else {
        e0 = make_float4(-1e30f, -1e30f, -1e30f, -1e30f);
    }
    // ---- exp (no max subtraction) + wave sum ----
    float4 ex;
    ex.x = __expf(e0.x); ex.y = __expf(e0.y);
    ex.z = __expf(e0.z); ex.w = __expf(e0.w);    // invalid lanes -> 0
    float4 sm = ex;
#pragma unroll
    for (int off = 1; off < 64; off <<= 1) {
        sm.x += __shfl_xor(sm.x, off, 64);
        sm.y += __shfl_xor(sm.y, off, 64);
        sm.z += __shfl_xor(sm.z, off, 64);
        sm.w += __shfl_xor(sm.w, off, 64);
    }
    // ---- normalized weights (rcp) + row offsets -> LDS ----
    float4 wgt;
    wgt.x = ex.x * __builtin_amdgcn_rcpf(sm.x);
    wgt.y = ex.y * __builtin_amdgcn_rcpf(sm.y);
    wgt.z = ex.z * __builtin_amdgcn_rcpf(sm.z);
    wgt.w = ex.w * __builtin_amdgcn_rcpf(sm.w);
    *(float4*)&s_w[wv][lane * 4] = wgt;
    s_off[wv][lane] = s << 8;                    // fp8 row = 256 B

    // ---- gather: exact groups of 4 edges, 2-deep pipeline ----
    const float* s_wf = &s_w[wv][0];
    const int* s_of = &s_off[wv][0];
    const int myhead4 = (lane & 15) >> 2;
    const int l4 = lane >> 4;
    const char* Prow = (const char*)P + ((lane & 15) << 4);
    f32x2 acc[8];
#pragma unroll
    for (int a = 0; a < 8; ++a) acc[a] = (f32x2){0.f, 0.f};
    const int nit = (deg + 3) >> 2;              // <= 16

#define DEQ_FMA(pv, wsc)                                                     \
    {                                                                        \
        f32x2 w2 = {wsc, wsc};                                               \
        f32x2 lo, hi;                                                        \
        lo = __builtin_amdgcn_cvt_pk_f32_fp8((pv).x, false);                 \
        hi = __builtin_amdgcn_cvt_pk_f32_fp8((pv).x, true);                  \
        acc[0] = pkfma(w2, lo, acc[0]); acc[1] = pkfma(w2, hi, acc[1]);      \
        lo = __builtin_amdgcn_cvt_pk_f32_fp8((pv).y, false);                 \
        hi = __builtin_amdgcn_cvt_pk_f32_fp8((pv).y, true);                  \
        acc[2] = pkfma(w2, lo, acc[2]); acc[3] = pkfma(w2, hi, acc[3]);      \
        lo = __builtin_amdgcn_cvt_pk_f32_fp8((pv).z, false);                 \
        hi = __builtin_amdgcn_cvt_pk_f32_fp8((pv).z, true);                  \
        acc[4] = pkfma(w2, lo, acc[4]); acc[5] = pkfma(w2, hi, acc[5]);      \
        lo = __builtin_amdgcn_cvt_pk_f32_fp8((pv).w, false);                 \
        hi = __builtin_amdgcn_cvt_pk_f32_fp8((pv).w, true);                  \
        acc[6] = pkfma(w2, lo, acc[6]); acc[7] = pkfma(w2, hi, acc[7]);      \
    }

#if USE_FP8
    // prologue: group 0
    int off0 = s_of[l4];
    float w0 = s_wf[l4 * 4 + myhead4];
    uint4 pv0 = *(const uint4*)(Prow + off0);
    for (int i = 1; i < nit; ++i) {
        int esl = i * 4 + l4;
        int off1 = s_of[esl];
        float w1 = s_wf[esl * 4 + myhead4];
        uint4 pv1 = *(const uint4*)(Prow + off1);   // issue next load
        DEQ_FMA(pv0, w0);                            // dequant current
        off0 = off1; w0 = w1; pv0 = pv1;
    }
    DEQ_FMA(pv0, w0);
#else
    for (int i = 0; i < nit; ++i) {
        int esl = i * 4 + l4;
        float w1 = s_wf[esl * 4 + myhead4];
        int off1 = s_of[esl];
        uint4 pv = *(const uint4*)(Prow + off1);
        f32x2 w2 = {w1, w1};
        unsigned int dws[4] = {pv.x, pv.y, pv.z, pv.w};
#pragma unroll
        for (int q = 0; q < 4; ++q) {
            f32x2 v2;
            v2[0] = bfbits2f(dws[q] << 16);
            v2[1] = bfbits2f(dws[q] & 0xffff0000u);
            acc[q] = pkfma(w2, v2, acc[q]);
        }
    }
#endif
#undef DEQ_FMA

    // ---- combine across the 4 lane-groups (same lane&15) ----
#pragma unroll
    for (int a = 0; a < 8; ++a) {
        acc[a][0] += __shfl_xor(acc[a][0], 16, 64);
        acc[a][1] += __shfl_xor(acc[a][1], 16, 64);
        acc[a][0] += __shfl_xor(acc[a][0], 32, 64);
        acc[a][1] += __shfl_xor(acc[a][1], 32, 64);
    }
    if (lane < 16) {
        unsigned int ow[8];
#pragma unroll
        for (int a = 0; a < 8; ++a) {
            float2 bb = *(const float2*)&bias[lane * 16 + a * 2];
            float v0 = acc[a][0] + bb.x;
            float v1 = acc[a][1] + bb.y;
            if (do_elu) {
                v0 = (v0 > 0.f) ? v0 : (__expf(v0) - 1.f);
                v1 = (v1 > 0.f) ? v1 : (__expf(v1) - 1.f);
            }
            ow[a] = (unsigned int)f2bf(v0) | ((unsigned int)f2bf(v1) << 16);
        }
        uint4 o0 = {ow[0], ow[1], ow[2], ow[3]};
        uint4 o1 = {ow[4], ow[5], ow[6], ow[7]};
        char* obase = (char*)out + (size_t)d * 512 + lane * 32;
        *(uint4*)obase = o0;
        *(uint4*)(obase + 16) = o1;
    }
}

// ---------------- mean pool (column sums, bf16 input) ----------------

__global__ __launch_bounds__(256) void k_pool(const unsigned short* __restrict__ A, float* __restrict__ pooled, int N) {
    int t = threadIdx.x;
    float acc = 0.f;
    for (int r = blockIdx.x; r < N; r += gridDim.x)
        acc += bfbits2f(((unsigned int)A[(size_t)r * 256 + t]) << 16);
    atomicAdd(&pooled[t], acc);
}

// ---------------- classifier + softmax ----------------

__global__ void k_final(const float* __restrict__ pooled, const float* __restrict__ clsW,
                        const float* __restrict__ clsb, float* __restrict__ out, int N) {
    int t = threadIdx.x;  // 64 threads
    float logit = -1e30f;
    if (t < 16) {
        float acc = 0.f;
        for (int k = 0; k < 256; ++k)
            acc = fmaf(pooled[k], clsW[k * 16 + t], acc);
        logit = acc / (float)N + clsb[t];
    }
    float mx = logit;
#pragma unroll
    for (int off = 1; off < 16; off <<= 1) mx = fmaxf(mx, __shfl_xor(mx, off, 64));
    float ex = __expf(logit - mx);
    float sm = ex;
#pragma unroll
    for (int off = 1; off < 16; off <<= 1) sm += __shfl_xor(sm, off, 64);
    if (t < 16) out[t] = ex / sm;
}

// ---------------- launch ----------------

extern "C" void kernel_launch(void* const* d_in, const int* in_sizes, int n_in,
                              void* d_out, int out_size, void* d_ws, size_t ws_size,
                              hipStream_t stream) {
    const float* x     = (const float*)d_in[0];
    const int*   ei    = (const int*)d_in[1];
    const float* W0    = (const float*)d_in[2];
    const float* a0src = (const float*)d_in[3];
    const float* a0dst = (const float*)d_in[4];
    const float* b0    = (const float*)d_in[5];
    const float* W1    = (const float*)d_in[6];
    const float* a1src = (const float*)d_in[7];
    const float* a1dst = (const float*)d_in[8];
    const float* b1    = (const float*)d_in[9];
    const float* clsW  = (const float*)d_in[10];
    const float* clsb  = (const float*)d_in[11];
    float* out = (float*)d_out;

    const int N = in_sizes[0] / 64;   // 50000
    const int E = in_sizes[1] / 2;    // 800000

    char* w = (char*)d_ws;
    auto alloc = [&](size_t bytes) {
        char* p = w;
        w += (bytes + 255) & ~(size_t)255;
        return p;
    };
    unsigned short* W0T  = (unsigned short*)alloc((size_t)256 * 64 * 2);
    unsigned short* W1T  = (unsigned short*)alloc((size_t)256 * 256 * 2);
    unsigned char*  P    = (unsigned char*)alloc((size_t)N * 256 * 2);  // sized for bf16 fallback
    unsigned short* A    = (unsigned short*)alloc((size_t)N * 256 * 2);
    float* alsrc  = (float*)alloc((size_t)N * 4 * 4);
    float* aldst  = (float*)alloc((size_t)N * 4 * 4);
    int*   adj    = (int*)alloc((size_t)N * MAXDEG * 4);
    int*   cursor = (int*)alloc((size_t)N * 4);
    float* pooled = (float*)alloc(256 * 4);

    // prep: weight transposes + zero cursor/pooled (small kernel)
    const int nb_prep = 320 + (N + 255) / 256;   // 516 blocks
    k_prep<<<nb_prep, 256, 0, stream>>>(W0, W0T, W1, W1T, cursor, pooled, N);

    // graph build
    k_fill_xcd<<<NGROUP * 104, 256, 0, stream>>>(ei, cursor, adj, N, E);

    const int GB = (N + 63) / 64;  // 782

    // ---- layer 0 (A = f32 x, converted in-register) ----
    k_gemm_mfma<64, true><<<GB, 256, 0, stream>>>(x, W0T, a0src, a0dst, P, alsrc, aldst, N);
    k_agg<<<(N + 3) / 4, 256, 0, stream>>>(P, alsrc, aldst, cursor, adj, b0, A, N, /*do_elu=*/1);

    // ---- layer 1 (A = bf16 activations) ----
    k_gemm_mfma<256, false><<<GB, 256, 0, stream>>>(A, W1T, a1src, a1dst, P, alsrc, aldst, N);
    k_agg<<<(N + 3) / 4, 256, 0, stream>>>(P, alsrc, aldst, cursor, adj, b1, A, N, /*do_elu=*/0);

    // ---- pool + classify + softmax ----
    k_pool<<<256, 256, 0, stream>>>(A, pooled, N);
    k_final<<<1, 64, 0, stream>>>(pooled, clsW, clsb, out, N);
}